// Round 9
// baseline (767.462 us; speedup 1.0000x reference)
//
#include <hip/hip_runtime.h>
#include <hip/hip_bf16.h>

#define V_N 100000
#define VP  100096          // padded to multiple of 64
#define E_N 800000
#define NVEH 16
#define LN_EPS 1e-5f
#define NTILES (VP / 64)    // 1564
#define MSTR 132            // LDS msg row stride (floats)

typedef unsigned int uint;
typedef unsigned short ushort;
typedef __attribute__((ext_vector_type(8))) short bf8_t;   // 8 bf16 in 4 VGPRs
typedef __attribute__((ext_vector_type(4))) float f4_t;

__device__ __forceinline__ float bf2f(ushort u) {
    union { uint i; float f; } c; c.i = ((uint)u) << 16; return c.f;
}
__device__ __forceinline__ ushort f2bf(float f) {
    union { float f; uint i; } c; c.f = f; uint x = c.i;
    return (ushort)((x + 0x7FFFu + ((x >> 16) & 1u)) >> 16);   // RNE
}
__device__ __forceinline__ uint pk2(float a, float b) {
    return (uint)f2bf(a) | ((uint)f2bf(b) << 16);
}

// ---------------- generic weight pre-pack: W[krows][128] f32 -> frag bf16 uint4 ----------------
__global__ __launch_bounds__(256) void k_pack(const float* __restrict__ W, uint4* __restrict__ dst,
                                              int nslots, int krows) {
    int slot = blockIdx.x * 256 + threadIdx.x;
    if (slot >= nslots) return;
    int ks = slot >> 9;
    int ct = (slot >> 6) & 7;
    int l  = slot & 63;
    int k0 = ks * 32 + ((l >> 4) << 3);
    int col = (ct << 4) + (l & 15);
    ushort u[8];
#pragma unroll
    for (int e = 0; e < 8; ++e) {
        int k = k0 + e;
        u[e] = (k < krows) ? f2bf(W[(size_t)k * 128 + col]) : (ushort)0;
    }
    uint4 p;
    p.x = (uint)u[0] | ((uint)u[1] << 16);
    p.y = (uint)u[2] | ((uint)u[3] << 16);
    p.z = (uint)u[4] | ((uint)u[5] << 16);
    p.w = (uint)u[6] | ((uint)u[7] << 16);
    dst[slot] = p;
}

// ---------------- in-degree count ----------------
__global__ __launch_bounds__(256) void k_count(const int* __restrict__ dst, int* __restrict__ cnt) {
    int i = blockIdx.x * blockDim.x + threadIdx.x;
    if (i < E_N) atomicAdd(&cnt[dst[i]], 1);
}

// ---------------- 3-kernel exclusive scan (1024 elems/block) ----------------
__global__ __launch_bounds__(256) void k_scan1(const int* __restrict__ cnt, int* __restrict__ rowptr,
                                               int* __restrict__ part) {
    __shared__ int sh[256];
    const int tid = threadIdx.x;
    const int base = blockIdx.x * 1024 + tid * 4;
    int v0 = (base + 0 < V_N) ? cnt[base + 0] : 0;
    int v1 = (base + 1 < V_N) ? cnt[base + 1] : 0;
    int v2 = (base + 2 < V_N) ? cnt[base + 2] : 0;
    int v3 = (base + 3 < V_N) ? cnt[base + 3] : 0;
    int s = v0 + v1 + v2 + v3;
    sh[tid] = s; __syncthreads();
    for (int off = 1; off < 256; off <<= 1) {
        int t = (tid >= off) ? sh[tid - off] : 0;
        __syncthreads();
        sh[tid] += t;
        __syncthreads();
    }
    int excl = sh[tid] - s;
    if (tid == 255) part[blockIdx.x] = sh[255];
    int run = excl;
    if (base + 0 < V_N) rowptr[base + 0] = run; run += v0;
    if (base + 1 < V_N) rowptr[base + 1] = run; run += v1;
    if (base + 2 < V_N) rowptr[base + 2] = run; run += v2;
    if (base + 3 < V_N) rowptr[base + 3] = run;
}

__global__ __launch_bounds__(128) void k_scan2(const int* __restrict__ part, int* __restrict__ pex, int nb) {
    __shared__ int sh[128];
    const int tid = threadIdx.x;
    int v = (tid < nb) ? part[tid] : 0;
    sh[tid] = v; __syncthreads();
    for (int off = 1; off < 128; off <<= 1) {
        int t = (tid >= off) ? sh[tid - off] : 0;
        __syncthreads();
        sh[tid] += t;
        __syncthreads();
    }
    if (tid < nb) pex[tid] = sh[tid] - v;
}

__global__ __launch_bounds__(256) void k_scan3(int* __restrict__ rowptr, const int* __restrict__ pex,
                                               int* __restrict__ cursor) {
    int i = blockIdx.x * 256 + threadIdx.x;
    if (i < V_N) {
        int rp = rowptr[i] + pex[i >> 10];
        rowptr[i] = rp;
        cursor[i] = rp;
    }
    if (i == 0) rowptr[V_N] = E_N;
}

__global__ __launch_bounds__(256) void k_scatter(const int* __restrict__ src, const int* __restrict__ dst,
                                                 int* __restrict__ cursor, int4* __restrict__ pes4) {
    int e = blockIdx.x * 256 + threadIdx.x;
    if (e < E_N) {
        int d = dst[e];
        int p = atomicAdd(&cursor[d], 1);
        pes4[p] = make_int4(e, src[e], d, 0);
    }
}

// ---------------- node projection: hb = bf16(concat(Z, meta, 0pad) @ Wp + bp) via MFMA ----------------
__global__ __launch_bounds__(256) void k_nodeproj(const float* __restrict__ Z, const float* __restrict__ meta,
                                                  const uint4* __restrict__ Bpk, const float* __restrict__ b,
                                                  ushort* __restrict__ hb) {
    __shared__ uint4 Bs4[2560];   // 5 ks x 8 ct x 64 lanes, 40 KB
    const int tid = threadIdx.x;
    for (int slot = tid; slot < 2560; slot += 256) Bs4[slot] = Bpk[slot];
    __syncthreads();
    const int lane = tid & 63, wid = tid >> 6;
    const int l15 = lane & 15, l4 = lane >> 4;
    float bcol[8];
#pragma unroll
    for (int ct = 0; ct < 8; ++ct) bcol[ct] = b[ct * 16 + l15];
    const int tile = blockIdx.x;
    int rowA = tile * 64 + wid * 16 + l15;
    int rowAc = rowA < V_N ? rowA : V_N - 1;      // clamp: avoid OOB input reads
    const float* zp = Z + (size_t)rowAc * 128;
    union { uint4 u; bf8_t b; } afr[5];
#pragma unroll
    for (int ks = 0; ks < 4; ++ks) {
        int k0 = ks * 32 + l4 * 8;
        float4 f0 = *(const float4*)(zp + k0);
        float4 f1 = *(const float4*)(zp + k0 + 4);
        afr[ks].u.x = pk2(f0.x, f0.y);
        afr[ks].u.y = pk2(f0.z, f0.w);
        afr[ks].u.z = pk2(f1.x, f1.y);
        afr[ks].u.w = pk2(f1.z, f1.w);
    }
    {
        const float* mp = meta + (size_t)rowAc * 10;
        int f0 = l4 * 8;
        ushort u[8];
#pragma unroll
        for (int e = 0; e < 8; ++e) {
            int f = f0 + e;
            u[e] = (f < 10) ? f2bf(mp[f]) : (ushort)0;
        }
        afr[4].u.x = (uint)u[0] | ((uint)u[1] << 16);
        afr[4].u.y = (uint)u[2] | ((uint)u[3] << 16);
        afr[4].u.z = (uint)u[4] | ((uint)u[5] << 16);
        afr[4].u.w = (uint)u[6] | ((uint)u[7] << 16);
    }
    f4_t acc[8];
#pragma unroll
    for (int ct = 0; ct < 8; ++ct) acc[ct] = (f4_t){bcol[ct], bcol[ct], bcol[ct], bcol[ct]};
#pragma unroll
    for (int ks = 0; ks < 5; ++ks) {
#pragma unroll
        for (int ct = 0; ct < 8; ++ct) {
            union { uint4 u; bf8_t b; } cb; cb.u = Bs4[(ks * 8 + ct) * 64 + lane];
            acc[ct] = __builtin_amdgcn_mfma_f32_16x16x32_bf16(afr[ks].b, cb.b, acc[ct], 0, 0, 0);
        }
    }
    const int rowC0 = tile * 64 + wid * 16 + l4 * 4;
#pragma unroll
    for (int ct = 0; ct < 8; ++ct) {
        int col = ct * 16 + l15;
#pragma unroll
        for (int r = 0; r < 4; ++r) {
            int row = rowC0 + r;
            if (row < V_N) hb[(size_t)row * 128 + col] = f2bf(acc[ct][r]);
        }
    }
}

// ---------------- GEMM1: tb = bf16(hb @ W1b + b1), MFMA ----------------
__global__ __launch_bounds__(256) void k_gemm1(const ushort* __restrict__ hb, const uint4* __restrict__ Bpk,
                                               const float* __restrict__ b, ushort* __restrict__ tb) {
    __shared__ uint4 Bs4[2048];
    const int tid = threadIdx.x;
    for (int slot = tid; slot < 2048; slot += 256) Bs4[slot] = Bpk[slot];
    __syncthreads();
    const int lane = tid & 63, wid = tid >> 6;
    const int l15 = lane & 15, l4 = lane >> 4;
    float bcol[8];
#pragma unroll
    for (int ct = 0; ct < 8; ++ct) bcol[ct] = b[ct * 16 + l15];
    const int tile = blockIdx.x;
    const int rowA = tile * 64 + wid * 16 + l15;
    const uint4* ap = (const uint4*)(hb + (size_t)rowA * 128);
    f4_t acc[8];
#pragma unroll
    for (int ct = 0; ct < 8; ++ct) acc[ct] = (f4_t){bcol[ct], bcol[ct], bcol[ct], bcol[ct]};
#pragma unroll
    for (int ks = 0; ks < 4; ++ks) {
        union { uint4 u; bf8_t b; } ca; ca.u = ap[ks * 4 + l4];
#pragma unroll
        for (int ct = 0; ct < 8; ++ct) {
            union { uint4 u; bf8_t b; } cb; cb.u = Bs4[(ks * 8 + ct) * 64 + lane];
            acc[ct] = __builtin_amdgcn_mfma_f32_16x16x32_bf16(ca.b, cb.b, acc[ct], 0, 0, 0);
        }
    }
    const int rowC0 = tile * 64 + wid * 16 + l4 * 4;
#pragma unroll
    for (int ct = 0; ct < 8; ++ct) {
        int col = ct * 16 + l15;
#pragma unroll
        for (int r = 0; r < 4; ++r) {
            int row = rowC0 + r;
            if (row < V_N) tb[(size_t)row * 128 + col] = f2bf(acc[ct][r]);
        }
    }
}

// ---------------- fused edge kernel: per 64 perm rows, MFMA ea@W1a -> LDS,
//                  then segmented sum of relu(tb[src] + U) into fp32 S ----------------
__global__ __launch_bounds__(256) void k_edge_fused(const float* __restrict__ ea,
                                                    const int4* __restrict__ pes4,
                                                    const uint4* __restrict__ Bpk,
                                                    const ushort* __restrict__ tb,
                                                    const int* __restrict__ rowptr,
                                                    float* __restrict__ S) {
    __shared__ uint4 Bs4[512];          // W1a frag (K=32, rows 16-31 zero), 8 KB
    __shared__ float msg[64 * MSTR];    // raw U tile, 33.8 KB
    const int tid = threadIdx.x;
    for (int slot = tid; slot < 512; slot += 256) Bs4[slot] = Bpk[slot];
    __syncthreads();
    const int lane = tid & 63, wid = tid >> 6;
    const int l15 = lane & 15, l4 = lane >> 4;
    const long base = (long)blockIdx.x * 64;
    const long ebase = base + wid * 16;
    // --- MFMA stage: U[rows ebase..ebase+15] = ea @ W1a ---
    union { uint4 u; bf8_t b; } afr;
    afr.u = make_uint4(0u, 0u, 0u, 0u);
    if (l4 < 2) {
        int eidx = pes4[ebase + l15].x;
        const float* ep = ea + (size_t)eidx * 16 + l4 * 8;
        float4 f0 = *(const float4*)ep;
        float4 f1 = *(const float4*)(ep + 4);
        afr.u.x = pk2(f0.x, f0.y);
        afr.u.y = pk2(f0.z, f0.w);
        afr.u.z = pk2(f1.x, f1.y);
        afr.u.w = pk2(f1.z, f1.w);
    }
    f4_t acc[8];
#pragma unroll
    for (int ct = 0; ct < 8; ++ct) acc[ct] = (f4_t){0.f, 0.f, 0.f, 0.f};
#pragma unroll
    for (int ct = 0; ct < 8; ++ct) {
        union { uint4 u; bf8_t b; } cb; cb.u = Bs4[ct * 64 + lane];
        acc[ct] = __builtin_amdgcn_mfma_f32_16x16x32_bf16(afr.b, cb.b, acc[ct], 0, 0, 0);
    }
    // spill raw U tile to LDS (local row = wid*16 + l4*4 + r)
    const int lr0 = wid * 16 + l4 * 4;
#pragma unroll
    for (int ct = 0; ct < 8; ++ct) {
        int col = ct * 16 + l15;
#pragma unroll
        for (int r = 0; r < 4; ++r) msg[(lr0 + r) * MSTR + col] = acc[ct][r];
    }
    __syncthreads();
    // --- reduction stage: wave q owns rows [q*16, q*16+16), lane owns col pair co ---
    const int q = wid;
    const int co = 2 * lane;
    float a0 = 0.f, a1 = 0.f;
    int ja = q * 16;
    int vcur = pes4[base + ja].z;
#pragma unroll 4
    for (int j = q * 16; j < q * 16 + 16; ++j) {
        int4 pe = pes4[base + j];
        if (pe.z != vcur) {
            // flush run [ja, j)
            int st = rowptr[vcur], en = rowptr[vcur + 1];
            if (st == base + ja && en == base + j) {
                S[(size_t)vcur * 128 + co] = a0;
                S[(size_t)vcur * 128 + co + 1] = a1;
            } else {
                atomicAdd(&S[(size_t)vcur * 128 + co], a0);
                atomicAdd(&S[(size_t)vcur * 128 + co + 1], a1);
            }
            vcur = pe.z; ja = j; a0 = 0.f; a1 = 0.f;
        }
        float2 m = *(const float2*)&msg[j * MSTR + co];
        uint tv = *(const uint*)(tb + (size_t)pe.y * 128 + co);
        a0 += fmaxf(bf2f((ushort)(tv & 0xffffu)) + m.x, 0.f);
        a1 += fmaxf(bf2f((ushort)(tv >> 16)) + m.y, 0.f);
    }
    {   // final flush of run [ja, q*16+16)
        int jb = q * 16 + 16;
        int st = rowptr[vcur], en = rowptr[vcur + 1];
        if (st == base + ja && en == base + jb) {
            S[(size_t)vcur * 128 + co] = a0;
            S[(size_t)vcur * 128 + co + 1] = a1;
        } else {
            atomicAdd(&S[(size_t)vcur * 128 + co], a0);
            atomicAdd(&S[(size_t)vcur * 128 + co + 1], a1);
        }
    }
}

// ---------------- node update: hb = bf16(LN(hb + (S/cnt)@W2 + b2*mask)), MFMA + fused LN ----------------
__global__ __launch_bounds__(256) void k_node_update(const float* __restrict__ S, ushort* __restrict__ hb,
                                                     const int* __restrict__ cnt,
                                                     const uint4* __restrict__ Bpk, const float* __restrict__ b2,
                                                     const float* __restrict__ g, const float* __restrict__ bt) {
    __shared__ uint4 Bs4[2048];
    const int tid = threadIdx.x;
    for (int slot = tid; slot < 2048; slot += 256) Bs4[slot] = Bpk[slot];
    __syncthreads();
    const int lane = tid & 63, wid = tid >> 6;
    const int l15 = lane & 15, l4 = lane >> 4;
    float b2c[8], gc[8], btc[8];
#pragma unroll
    for (int ct = 0; ct < 8; ++ct) {
        int col = ct * 16 + l15;
        b2c[ct] = b2[col]; gc[ct] = g[col]; btc[ct] = bt[col];
    }
    const int tile = blockIdx.x;
    const int rowA = tile * 64 + wid * 16 + l15;
    const int rowAc = rowA < V_N ? rowA : V_N - 1;
    {
    }
    int ca_ = cnt[rowAc];
    const float invA = 1.f / (float)(ca_ > 1 ? ca_ : 1);
    const float* sp = S + (size_t)rowAc * 128;
    f4_t acc[8];
#pragma unroll
    for (int ct = 0; ct < 8; ++ct) acc[ct] = (f4_t){0.f, 0.f, 0.f, 0.f};
#pragma unroll
    for (int ks = 0; ks < 4; ++ks) {
        int k0 = ks * 32 + l4 * 8;
        float4 f0 = *(const float4*)(sp + k0);
        float4 f1 = *(const float4*)(sp + k0 + 4);
        union { uint4 u; bf8_t b; } ca;
        ca.u.x = pk2(f0.x * invA, f0.y * invA);
        ca.u.y = pk2(f0.z * invA, f0.w * invA);
        ca.u.z = pk2(f1.x * invA, f1.y * invA);
        ca.u.w = pk2(f1.z * invA, f1.w * invA);
#pragma unroll
        for (int ct = 0; ct < 8; ++ct) {
            union { uint4 u; bf8_t b; } cb; cb.u = Bs4[(ks * 8 + ct) * 64 + lane];
            acc[ct] = __builtin_amdgcn_mfma_f32_16x16x32_bf16(ca.b, cb.b, acc[ct], 0, 0, 0);
        }
    }
    const int rowC0 = tile * 64 + wid * 16 + l4 * 4;
    float mask[4];
#pragma unroll
    for (int r = 0; r < 4; ++r) {
        int row = rowC0 + r;
        int dg = (row < V_N) ? cnt[row] : 0;
        mask[r] = (dg > 0) ? 1.f : 0.f;
    }
    float x[8][4];
#pragma unroll
    for (int ct = 0; ct < 8; ++ct) {
        int col = ct * 16 + l15;
#pragma unroll
        for (int r = 0; r < 4; ++r) {
            float hv = bf2f(hb[(size_t)(rowC0 + r) * 128 + col]);
            x[ct][r] = hv + acc[ct][r] + b2c[ct] * mask[r];
        }
    }
#pragma unroll
    for (int r = 0; r < 4; ++r) {
        float s = 0.f;
#pragma unroll
        for (int ct = 0; ct < 8; ++ct) s += x[ct][r];
        s += __shfl_xor(s, 1); s += __shfl_xor(s, 2);
        s += __shfl_xor(s, 4); s += __shfl_xor(s, 8);
        float mean = s * (1.f / 128.f);
        float vv = 0.f;
#pragma unroll
        for (int ct = 0; ct < 8; ++ct) { float d = x[ct][r] - mean; vv = fmaf(d, d, vv); }
        vv += __shfl_xor(vv, 1); vv += __shfl_xor(vv, 2);
        vv += __shfl_xor(vv, 4); vv += __shfl_xor(vv, 8);
        float rs = rsqrtf(vv * (1.f / 128.f) + LN_EPS);
        int row = rowC0 + r;
        bool ok = row < V_N;
#pragma unroll
        for (int ct = 0; ct < 8; ++ct) {
            int col = ct * 16 + l15;
            float y = (x[ct][r] - mean) * rs * gc[ct] + btc[ct];
            if (ok) hb[(size_t)row * 128 + col] = f2bf(y);
        }
    }
}

// ---------------- final: out = LN(hb[cur] + props MLP) ----------------
__global__ __launch_bounds__(128) void k_final(const ushort* __restrict__ hb, const int* __restrict__ cur,
                                               const float* __restrict__ veh,
                                               const float* __restrict__ pw1, const float* __restrict__ pb1,
                                               const float* __restrict__ pw2, const float* __restrict__ pb2,
                                               const float* __restrict__ g, const float* __restrict__ bt,
                                               float* __restrict__ out) {
    __shared__ float hid[128];
    __shared__ float red[2];
    const int i = blockIdx.x;
    const int j = threadIdx.x;
    float a = pb1[j];
#pragma unroll
    for (int f = 0; f < 8; ++f) a = fmaf(veh[i * 8 + f], pw1[f * 128 + j], a);
    hid[j] = fmaxf(a, 0.f);
    __syncthreads();
    float o = pb2[j] + bf2f(hb[(size_t)cur[i] * 128 + j]);
    for (int k = 0; k < 128; ++k) o = fmaf(hid[k], pw2[k * 128 + j], o);
    const int lane = j & 63, wid = j >> 6;
    float s = o;
#pragma unroll
    for (int off = 32; off > 0; off >>= 1) s += __shfl_xor(s, off);
    if (lane == 0) red[wid] = s;
    __syncthreads();
    float mean = (red[0] + red[1]) * (1.f / 128.f);
    __syncthreads();
    float d = o - mean;
    float vv = d * d;
#pragma unroll
    for (int off = 32; off > 0; off >>= 1) vv += __shfl_xor(vv, off);
    if (lane == 0) red[wid] = vv;
    __syncthreads();
    float var = (red[0] + red[1]) * (1.f / 128.f);
    float r = rsqrtf(var + LN_EPS);
    out[i * 128 + j] = d * r * g[j] + bt[j];
}

extern "C" void kernel_launch(void* const* d_in, const int* in_sizes, int n_in,
                              void* d_out, int out_size, void* d_ws, size_t ws_size,
                              hipStream_t stream) {
    const float* Z    = (const float*)d_in[0];
    const float* meta = (const float*)d_in[1];
    const float* veh  = (const float*)d_in[2];
    const float* ea   = (const float*)d_in[3];
    const int*   esrc = (const int*)d_in[4];
    const int*   edst = (const int*)d_in[5];
    const int*   cur  = (const int*)d_in[6];
    const float* npw  = (const float*)d_in[7];
    const float* npb  = (const float*)d_in[8];
    const float* w1   = (const float*)d_in[9];
    const float* b1   = (const float*)d_in[10];
    const float* w2   = (const float*)d_in[11];
    const float* b2   = (const float*)d_in[12];
    const float* lng  = (const float*)d_in[13];
    const float* lnb  = (const float*)d_in[14];
    const float* pw1  = (const float*)d_in[15];
    const float* pb1  = (const float*)d_in[16];
    const float* pw2  = (const float*)d_in[17];
    const float* pb2  = (const float*)d_in[18];
    const float* rog  = (const float*)d_in[19];
    const float* rob  = (const float*)d_in[20];

    ushort* hb = (ushort*)d_ws;                     // [VP][128] bf16
    ushort* tb = hb + (size_t)VP * 128;             // [VP][128] bf16
    float*  Sf = (float*)(tb + (size_t)VP * 128);   // [VP][128] f32 (raw relu-sums)
    int* cnt    = (int*)(Sf + (size_t)VP * 128);    // [VP]
    int* rowptr = cnt + VP;                         // [V+1]
    int* cursor = rowptr + VP;                      // [VP]
    int4* pes4  = (int4*)(cursor + VP);             // [E] {edge, src, dst, 0}
    int* part   = (int*)(pes4 + E_N);               // [128]
    int* pex    = part + 128;                       // [128]
    uint4* Bnp  = (uint4*)(pex + 128);              // [2560] packed nodeproj W
    uint4* Bw1b = Bnp + 2560;                       // [2][2048]
    uint4* Bw1a = Bw1b + 2 * 2048;                  // [2][512]
    uint4* Bw2  = Bw1a + 2 * 512;                   // [2][2048]
    float* out = (float*)d_out;

    const int NB = (V_N + 1023) / 1024;  // 98

    // --- weight pre-pack (frag-layout bf16) ---
    k_pack<<<10, 256, 0, stream>>>(npw, Bnp, 2560, 138);
    for (int l = 0; l < 2; ++l) {
        const float* W1b = w1 + (size_t)l * 144 * 128;
        const float* W1a = W1b + 128 * 128;
        k_pack<<<8, 256, 0, stream>>>(W1b, Bw1b + l * 2048, 2048, 128);
        k_pack<<<2, 256, 0, stream>>>(W1a, Bw1a + l * 512, 512, 16);
        k_pack<<<8, 256, 0, stream>>>(w2 + (size_t)l * 128 * 128, Bw2 + l * 2048, 2048, 128);
    }

    hipMemsetAsync(cnt, 0, VP * sizeof(int), stream);
    k_count<<<(E_N + 255) / 256, 256, 0, stream>>>(edst, cnt);
    k_scan1<<<NB, 256, 0, stream>>>(cnt, rowptr, part);
    k_scan2<<<1, 128, 0, stream>>>(part, pex, NB);
    k_scan3<<<(V_N + 255) / 256, 256, 0, stream>>>(rowptr, pex, cursor);
    k_scatter<<<(E_N + 255) / 256, 256, 0, stream>>>(esrc, edst, cursor, pes4);
    k_nodeproj<<<NTILES, 256, 0, stream>>>(Z, meta, Bnp, npb, hb);

    for (int l = 0; l < 2; ++l) {
        k_gemm1<<<NTILES, 256, 0, stream>>>(hb, Bw1b + l * 2048, b1 + l * 128, tb);
        hipMemsetAsync(Sf, 0, (size_t)V_N * 128 * sizeof(float), stream);
        k_edge_fused<<<E_N / 64, 256, 0, stream>>>(ea, pes4, Bw1a + l * 512, tb, rowptr, Sf);
        k_node_update<<<NTILES, 256, 0, stream>>>(Sf, hb, cnt, Bw2 + l * 2048,
                                                  b2 + l * 128, lng + l * 128, lnb + l * 128);
    }
    k_final<<<NVEH, 128, 0, stream>>>(hb, cur, veh, pw1, pb1, pw2, pb2, rog, rob, out);
}

// Round 11
// 607.799 us; speedup vs baseline: 1.2627x; 1.2627x over previous
//
#include <hip/hip_runtime.h>
#include <hip/hip_bf16.h>

#define V_N 100000
#define VP  100096          // padded to multiple of 64
#define E_N 800000
#define NVEH 16
#define LN_EPS 1e-5f
#define NTILES (VP / 64)    // 1564

typedef unsigned int uint;
typedef unsigned short ushort;
typedef unsigned char uchar;
typedef __attribute__((ext_vector_type(8))) short bf8_t;   // 8 bf16 in 4 VGPRs
typedef __attribute__((ext_vector_type(4))) float f4_t;

__device__ __forceinline__ float bf2f(ushort u) {
    union { uint i; float f; } c; c.i = ((uint)u) << 16; return c.f;
}
__device__ __forceinline__ ushort f2bf(float f) {
    union { float f; uint i; } c; c.f = f; uint x = c.i;
    return (ushort)((x + 0x7FFFu + ((x >> 16) & 1u)) >> 16);   // RNE
}
__device__ __forceinline__ uint pk2(float a, float b) {
    return (uint)f2bf(a) | ((uint)f2bf(b) << 16);
}

// ---------------- generic weight pre-pack: W[krows][128] f32 -> frag bf16 uint4 ----------------
__global__ __launch_bounds__(256) void k_pack(const float* __restrict__ W, uint4* __restrict__ dst,
                                              int nslots, int krows) {
    int slot = blockIdx.x * 256 + threadIdx.x;
    if (slot >= nslots) return;
    int ks = slot >> 9;
    int ct = (slot >> 6) & 7;
    int l  = slot & 63;
    int k0 = ks * 32 + ((l >> 4) << 3);
    int col = (ct << 4) + (l & 15);
    ushort u[8];
#pragma unroll
    for (int e = 0; e < 8; ++e) {
        int k = k0 + e;
        u[e] = (k < krows) ? f2bf(W[(size_t)k * 128 + col]) : (ushort)0;
    }
    uint4 p;
    p.x = (uint)u[0] | ((uint)u[1] << 16);
    p.y = (uint)u[2] | ((uint)u[3] << 16);
    p.z = (uint)u[4] | ((uint)u[5] << 16);
    p.w = (uint)u[6] | ((uint)u[7] << 16);
    dst[slot] = p;
}

// ---------------- in-degree count ----------------
__global__ __launch_bounds__(256) void k_count(const int* __restrict__ dst, int* __restrict__ cnt) {
    int i = blockIdx.x * blockDim.x + threadIdx.x;
    if (i < E_N) atomicAdd(&cnt[dst[i]], 1);
}

// ---------------- 3-kernel exclusive scan (1024 elems/block) ----------------
__global__ __launch_bounds__(256) void k_scan1(const int* __restrict__ cnt, int* __restrict__ rowptr,
                                               int* __restrict__ part) {
    __shared__ int sh[256];
    const int tid = threadIdx.x;
    const int base = blockIdx.x * 1024 + tid * 4;
    int v0 = (base + 0 < V_N) ? cnt[base + 0] : 0;
    int v1 = (base + 1 < V_N) ? cnt[base + 1] : 0;
    int v2 = (base + 2 < V_N) ? cnt[base + 2] : 0;
    int v3 = (base + 3 < V_N) ? cnt[base + 3] : 0;
    int s = v0 + v1 + v2 + v3;
    sh[tid] = s; __syncthreads();
    for (int off = 1; off < 256; off <<= 1) {
        int t = (tid >= off) ? sh[tid - off] : 0;
        __syncthreads();
        sh[tid] += t;
        __syncthreads();
    }
    int excl = sh[tid] - s;
    if (tid == 255) part[blockIdx.x] = sh[255];
    int run = excl;
    if (base + 0 < V_N) rowptr[base + 0] = run; run += v0;
    if (base + 1 < V_N) rowptr[base + 1] = run; run += v1;
    if (base + 2 < V_N) rowptr[base + 2] = run; run += v2;
    if (base + 3 < V_N) rowptr[base + 3] = run;
}

__global__ __launch_bounds__(128) void k_scan2(const int* __restrict__ part, int* __restrict__ pex, int nb) {
    __shared__ int sh[128];
    const int tid = threadIdx.x;
    int v = (tid < nb) ? part[tid] : 0;
    sh[tid] = v; __syncthreads();
    for (int off = 1; off < 128; off <<= 1) {
        int t = (tid >= off) ? sh[tid - off] : 0;
        __syncthreads();
        sh[tid] += t;
        __syncthreads();
    }
    if (tid < nb) pex[tid] = sh[tid] - v;
}

__global__ __launch_bounds__(256) void k_scan3(int* __restrict__ rowptr, const int* __restrict__ pex,
                                               int* __restrict__ cursor) {
    int i = blockIdx.x * 256 + threadIdx.x;
    if (i < V_N) {
        int rp = rowptr[i] + pex[i >> 10];
        rowptr[i] = rp;
        cursor[i] = rp;
    }
    if (i == 0) rowptr[V_N] = E_N;
}

__global__ __launch_bounds__(256) void k_scatter(const int* __restrict__ src, const int* __restrict__ dst,
                                                 int* __restrict__ cursor, int2* __restrict__ pes) {
    int e = blockIdx.x * 256 + threadIdx.x;
    if (e < E_N) {
        int d = dst[e];
        int p = atomicAdd(&cursor[d], 1);
        pes[p] = make_int2(e, src[e]);
    }
}

// ---------------- node projection: hb = bf16(concat(Z, meta, 0pad) @ Wp + bp) via MFMA ----------------
__global__ __launch_bounds__(256) void k_nodeproj(const float* __restrict__ Z, const float* __restrict__ meta,
                                                  const uint4* __restrict__ Bpk, const float* __restrict__ b,
                                                  ushort* __restrict__ hb) {
    __shared__ uint4 Bs4[2560];   // 5 ks x 8 ct x 64 lanes, 40 KB
    const int tid = threadIdx.x;
    for (int slot = tid; slot < 2560; slot += 256) Bs4[slot] = Bpk[slot];
    __syncthreads();
    const int lane = tid & 63, wid = tid >> 6;
    const int l15 = lane & 15, l4 = lane >> 4;
    float bcol[8];
#pragma unroll
    for (int ct = 0; ct < 8; ++ct) bcol[ct] = b[ct * 16 + l15];
    const int tile = blockIdx.x;
    int rowA = tile * 64 + wid * 16 + l15;
    int rowAc = rowA < V_N ? rowA : V_N - 1;      // clamp: avoid OOB input reads
    const float* zp = Z + (size_t)rowAc * 128;
    union { uint4 u; bf8_t b; } afr[5];
#pragma unroll
    for (int ks = 0; ks < 4; ++ks) {
        int k0 = ks * 32 + l4 * 8;
        float4 f0 = *(const float4*)(zp + k0);
        float4 f1 = *(const float4*)(zp + k0 + 4);
        afr[ks].u.x = pk2(f0.x, f0.y);
        afr[ks].u.y = pk2(f0.z, f0.w);
        afr[ks].u.z = pk2(f1.x, f1.y);
        afr[ks].u.w = pk2(f1.z, f1.w);
    }
    {
        const float* mp = meta + (size_t)rowAc * 10;
        int f0 = l4 * 8;
        ushort u[8];
#pragma unroll
        for (int e = 0; e < 8; ++e) {
            int f = f0 + e;
            u[e] = (f < 10) ? f2bf(mp[f]) : (ushort)0;
        }
        afr[4].u.x = (uint)u[0] | ((uint)u[1] << 16);
        afr[4].u.y = (uint)u[2] | ((uint)u[3] << 16);
        afr[4].u.z = (uint)u[4] | ((uint)u[5] << 16);
        afr[4].u.w = (uint)u[6] | ((uint)u[7] << 16);
    }
    f4_t acc[8];
#pragma unroll
    for (int ct = 0; ct < 8; ++ct) acc[ct] = (f4_t){bcol[ct], bcol[ct], bcol[ct], bcol[ct]};
#pragma unroll
    for (int ks = 0; ks < 5; ++ks) {
#pragma unroll
        for (int ct = 0; ct < 8; ++ct) {
            union { uint4 u; bf8_t b; } cb; cb.u = Bs4[(ks * 8 + ct) * 64 + lane];
            acc[ct] = __builtin_amdgcn_mfma_f32_16x16x32_bf16(afr[ks].b, cb.b, acc[ct], 0, 0, 0);
        }
    }
    const int rowC0 = tile * 64 + wid * 16 + l4 * 4;
#pragma unroll
    for (int ct = 0; ct < 8; ++ct) {
        int col = ct * 16 + l15;
#pragma unroll
        for (int r = 0; r < 4; ++r) {
            int row = rowC0 + r;
            if (row < V_N) hb[(size_t)row * 128 + col] = f2bf(acc[ct][r]);
        }
    }
}

// ---------------- GEMM1: tb = bf16(hb @ W1b + b1), MFMA ----------------
__global__ __launch_bounds__(256) void k_gemm1(const ushort* __restrict__ hb, const uint4* __restrict__ Bpk,
                                               const float* __restrict__ b, ushort* __restrict__ tb) {
    __shared__ uint4 Bs4[2048];
    const int tid = threadIdx.x;
    for (int slot = tid; slot < 2048; slot += 256) Bs4[slot] = Bpk[slot];
    __syncthreads();
    const int lane = tid & 63, wid = tid >> 6;
    const int l15 = lane & 15, l4 = lane >> 4;
    float bcol[8];
#pragma unroll
    for (int ct = 0; ct < 8; ++ct) bcol[ct] = b[ct * 16 + l15];
    const int tile = blockIdx.x;
    const int rowA = tile * 64 + wid * 16 + l15;
    const uint4* ap = (const uint4*)(hb + (size_t)rowA * 128);
    f4_t acc[8];
#pragma unroll
    for (int ct = 0; ct < 8; ++ct) acc[ct] = (f4_t){bcol[ct], bcol[ct], bcol[ct], bcol[ct]};
#pragma unroll
    for (int ks = 0; ks < 4; ++ks) {
        union { uint4 u; bf8_t b; } ca; ca.u = ap[ks * 4 + l4];
#pragma unroll
        for (int ct = 0; ct < 8; ++ct) {
            union { uint4 u; bf8_t b; } cb; cb.u = Bs4[(ks * 8 + ct) * 64 + lane];
            acc[ct] = __builtin_amdgcn_mfma_f32_16x16x32_bf16(ca.b, cb.b, acc[ct], 0, 0, 0);
        }
    }
    const int rowC0 = tile * 64 + wid * 16 + l4 * 4;
#pragma unroll
    for (int ct = 0; ct < 8; ++ct) {
        int col = ct * 16 + l15;
#pragma unroll
        for (int r = 0; r < 4; ++r) {
            int row = rowC0 + r;
            if (row < V_N) tb[(size_t)row * 128 + col] = f2bf(acc[ct][r]);
        }
    }
}

// ---------------- edge MLP GEMM: U[i] = fp8(ea[pes[i].x] @ W1a), perm order, PERMUTED byte layout ----
// stored byte index s = (col&15)*8 + (col>>4)  ->  each lane stores 8 contiguous bytes per row (uint2)
__global__ __launch_bounds__(256) void k_edge_mlp(const float* __restrict__ ea,
                                                  const int2* __restrict__ pes,
                                                  const uint4* __restrict__ Bpk,
                                                  uchar* __restrict__ U) {
    __shared__ uint4 Bs4[512];   // 8 ct x 64 lanes; K=32 (rows 0-15 real, 16-31 zero), 8 KB
    const int tid = threadIdx.x;
    for (int slot = tid; slot < 512; slot += 256) Bs4[slot] = Bpk[slot];
    __syncthreads();
    const int lane = tid & 63, wid = tid >> 6;
    const int l15 = lane & 15, l4 = lane >> 4;
    const long ebase = (long)blockIdx.x * 64 + wid * 16;   // 16 perm rows per wave
    union { uint4 u; bf8_t b; } afr;
    afr.u = make_uint4(0u, 0u, 0u, 0u);
    if (l4 < 2) {
        int eidx = pes[ebase + l15].x;
        const float* ep = ea + (size_t)eidx * 16 + l4 * 8;
        float4 f0 = *(const float4*)ep;
        float4 f1 = *(const float4*)(ep + 4);
        afr.u.x = pk2(f0.x, f0.y);
        afr.u.y = pk2(f0.z, f0.w);
        afr.u.z = pk2(f1.x, f1.y);
        afr.u.w = pk2(f1.z, f1.w);
    }
    f4_t acc[8];
#pragma unroll
    for (int ct = 0; ct < 8; ++ct) acc[ct] = (f4_t){0.f, 0.f, 0.f, 0.f};
#pragma unroll
    for (int ct = 0; ct < 8; ++ct) {
        union { uint4 u; bf8_t b; } cb; cb.u = Bs4[ct * 64 + lane];
        acc[ct] = __builtin_amdgcn_mfma_f32_16x16x32_bf16(afr.b, cb.b, acc[ct], 0, 0, 0);
    }
    const long rowC0 = ebase + l4 * 4;
#pragma unroll
    for (int r = 0; r < 4; ++r) {
        int p01 = __builtin_amdgcn_cvt_pk_fp8_f32(acc[0][r], acc[1][r], 0, false);
        int p23 = __builtin_amdgcn_cvt_pk_fp8_f32(acc[2][r], acc[3][r], 0, false);
        int p45 = __builtin_amdgcn_cvt_pk_fp8_f32(acc[4][r], acc[5][r], 0, false);
        int p67 = __builtin_amdgcn_cvt_pk_fp8_f32(acc[6][r], acc[7][r], 0, false);
        uint2 w;
        w.x = ((uint)p01 & 0xffffu) | ((uint)p23 << 16);
        w.y = ((uint)p45 & 0xffffu) | ((uint)p67 << 16);
        *(uint2*)(U + (size_t)(rowC0 + r) * 128 + l15 * 8) = w;
    }
}

// ---------------- edge aggregation: S[v] = bf16(mean_i relu(tb[src_i] + U[i])) ----------------
__global__ __launch_bounds__(256) void k_edge_agg2(const ushort* __restrict__ tb,
                                                   const uchar* __restrict__ U,
                                                   const int2* __restrict__ pes,
                                                   const int* __restrict__ rowptr,
                                                   ushort* __restrict__ S) {
    const int lane = threadIdx.x & 63;
    const int wid  = threadIdx.x >> 6;
    const int v = blockIdx.x * 4 + wid;
    if (v >= V_N) return;
    const int st = rowptr[v], en = rowptr[v + 1];
    const int co = 2 * lane;
    const int s0 = (co & 15) * 8 + (co >> 4);   // permuted byte index for col co (col co+1 at s0+8)
    float a0 = 0.f, a1 = 0.f;
    for (int i0 = st; i0 < en; i0 += 8) {
        const int n = en - i0;
        int idx[8];
#pragma unroll
        for (int j = 0; j < 8; ++j) idx[j] = (j < n) ? (i0 + j) : i0;
        int s[8];
#pragma unroll
        for (int j = 0; j < 8; ++j) s[j] = pes[idx[j]].y;
        uint tv[8]; uint uv[8];
#pragma unroll
        for (int j = 0; j < 8; ++j) {
            tv[j] = *(const uint*)(tb + (size_t)s[j] * 128 + co);
            const uchar* up = U + (size_t)idx[j] * 128 + s0;
            uv[j] = (uint)up[0] | ((uint)up[8] << 8);
        }
#pragma unroll
        for (int j = 0; j < 8; ++j) {
            auto uf = __builtin_amdgcn_cvt_pk_f32_fp8((int)uv[j], false);
            float p0 = bf2f((ushort)(tv[j] & 0xffffu)) + uf[0];
            float p1 = bf2f((ushort)(tv[j] >> 16)) + uf[1];
            if (j < n) { a0 += fmaxf(p0, 0.f); a1 += fmaxf(p1, 0.f); }
        }
    }
    int dg = en - st;
    float inv = 1.f / (float)(dg > 1 ? dg : 1);
    *(uint*)(S + (size_t)v * 128 + co) = pk2(a0 * inv, a1 * inv);
}

// ---------------- node update: hb = bf16(LN(hb + S@W2 + b2*mask)), MFMA + fused LN ----------------
__global__ __launch_bounds__(256) void k_node_update(const ushort* __restrict__ S, ushort* __restrict__ hb,
                                                     const int* __restrict__ cnt,
                                                     const uint4* __restrict__ Bpk, const float* __restrict__ b2,
                                                     const float* __restrict__ g, const float* __restrict__ bt) {
    __shared__ uint4 Bs4[2048];
    const int tid = threadIdx.x;
    for (int slot = tid; slot < 2048; slot += 256) Bs4[slot] = Bpk[slot];
    __syncthreads();
    const int lane = tid & 63, wid = tid >> 6;
    const int l15 = lane & 15, l4 = lane >> 4;
    float b2c[8], gc[8], btc[8];
#pragma unroll
    for (int ct = 0; ct < 8; ++ct) {
        int col = ct * 16 + l15;
        b2c[ct] = b2[col]; gc[ct] = g[col]; btc[ct] = bt[col];
    }
    const int tile = blockIdx.x;
    const int rowA = tile * 64 + wid * 16 + l15;
    const uint4* ap = (const uint4*)(S + (size_t)rowA * 128);
    f4_t acc[8];
#pragma unroll
    for (int ct = 0; ct < 8; ++ct) acc[ct] = (f4_t){0.f, 0.f, 0.f, 0.f};
#pragma unroll
    for (int ks = 0; ks < 4; ++ks) {
        union { uint4 u; bf8_t b; } ca; ca.u = ap[ks * 4 + l4];
#pragma unroll
        for (int ct = 0; ct < 8; ++ct) {
            union { uint4 u; bf8_t b; } cb; cb.u = Bs4[(ks * 8 + ct) * 64 + lane];
            acc[ct] = __builtin_amdgcn_mfma_f32_16x16x32_bf16(ca.b, cb.b, acc[ct], 0, 0, 0);
        }
    }
    const int rowC0 = tile * 64 + wid * 16 + l4 * 4;
    float mask[4];
#pragma unroll
    for (int r = 0; r < 4; ++r) {
        int row = rowC0 + r;
        int dg = (row < V_N) ? cnt[row] : 0;
        mask[r] = (dg > 0) ? 1.f : 0.f;
    }
    float x[8][4];
#pragma unroll
    for (int ct = 0; ct < 8; ++ct) {
        int col = ct * 16 + l15;
#pragma unroll
        for (int r = 0; r < 4; ++r) {
            float hv = bf2f(hb[(size_t)(rowC0 + r) * 128 + col]);
            x[ct][r] = hv + acc[ct][r] + b2c[ct] * mask[r];
        }
    }
#pragma unroll
    for (int r = 0; r < 4; ++r) {
        float s = 0.f;
#pragma unroll
        for (int ct = 0; ct < 8; ++ct) s += x[ct][r];
        s += __shfl_xor(s, 1); s += __shfl_xor(s, 2);
        s += __shfl_xor(s, 4); s += __shfl_xor(s, 8);
        float mean = s * (1.f / 128.f);
        float vv = 0.f;
#pragma unroll
        for (int ct = 0; ct < 8; ++ct) { float d = x[ct][r] - mean; vv = fmaf(d, d, vv); }
        vv += __shfl_xor(vv, 1); vv += __shfl_xor(vv, 2);
        vv += __shfl_xor(vv, 4); vv += __shfl_xor(vv, 8);
        float rs = rsqrtf(vv * (1.f / 128.f) + LN_EPS);
        int row = rowC0 + r;
        bool ok = row < V_N;
#pragma unroll
        for (int ct = 0; ct < 8; ++ct) {
            int col = ct * 16 + l15;
            float y = (x[ct][r] - mean) * rs * gc[ct] + btc[ct];
            if (ok) hb[(size_t)row * 128 + col] = f2bf(y);
        }
    }
}

// ---------------- final: out = LN(hb[cur] + props MLP) ----------------
__global__ __launch_bounds__(128) void k_final(const ushort* __restrict__ hb, const int* __restrict__ cur,
                                               const float* __restrict__ veh,
                                               const float* __restrict__ pw1, const float* __restrict__ pb1,
                                               const float* __restrict__ pw2, const float* __restrict__ pb2,
                                               const float* __restrict__ g, const float* __restrict__ bt,
                                               float* __restrict__ out) {
    __shared__ float hid[128];
    __shared__ float red[2];
    const int i = blockIdx.x;
    const int j = threadIdx.x;
    float a = pb1[j];
#pragma unroll
    for (int f = 0; f < 8; ++f) a = fmaf(veh[i * 8 + f], pw1[f * 128 + j], a);
    hid[j] = fmaxf(a, 0.f);
    __syncthreads();
    float o = pb2[j] + bf2f(hb[(size_t)cur[i] * 128 + j]);
    for (int k = 0; k < 128; ++k) o = fmaf(hid[k], pw2[k * 128 + j], o);
    const int lane = j & 63, wid = j >> 6;
    float s = o;
#pragma unroll
    for (int off = 32; off > 0; off >>= 1) s += __shfl_xor(s, off);
    if (lane == 0) red[wid] = s;
    __syncthreads();
    float mean = (red[0] + red[1]) * (1.f / 128.f);
    __syncthreads();
    float d = o - mean;
    float vv = d * d;
#pragma unroll
    for (int off = 32; off > 0; off >>= 1) vv += __shfl_xor(vv, off);
    if (lane == 0) red[wid] = vv;
    __syncthreads();
    float var = (red[0] + red[1]) * (1.f / 128.f);
    float r = rsqrtf(var + LN_EPS);
    out[i * 128 + j] = d * r * g[j] + bt[j];
}

extern "C" void kernel_launch(void* const* d_in, const int* in_sizes, int n_in,
                              void* d_out, int out_size, void* d_ws, size_t ws_size,
                              hipStream_t stream) {
    const float* Z    = (const float*)d_in[0];
    const float* meta = (const float*)d_in[1];
    const float* veh  = (const float*)d_in[2];
    const float* ea   = (const float*)d_in[3];
    const int*   esrc = (const int*)d_in[4];
    const int*   edst = (const int*)d_in[5];
    const int*   cur  = (const int*)d_in[6];
    const float* npw  = (const float*)d_in[7];
    const float* npb  = (const float*)d_in[8];
    const float* w1   = (const float*)d_in[9];
    const float* b1   = (const float*)d_in[10];
    const float* w2   = (const float*)d_in[11];
    const float* b2   = (const float*)d_in[12];
    const float* lng  = (const float*)d_in[13];
    const float* lnb  = (const float*)d_in[14];
    const float* pw1  = (const float*)d_in[15];
    const float* pb1  = (const float*)d_in[16];
    const float* pw2  = (const float*)d_in[17];
    const float* pb2  = (const float*)d_in[18];
    const float* rog  = (const float*)d_in[19];
    const float* rob  = (const float*)d_in[20];

    ushort* hb = (ushort*)d_ws;                     // [VP][128] bf16
    ushort* tb = hb + (size_t)VP * 128;             // [VP][128] bf16
    ushort* S  = tb + (size_t)VP * 128;             // [VP][128] bf16
    int* cnt    = (int*)(S + (size_t)VP * 128);     // [VP]
    int* rowptr = cnt + VP;                         // [V+1]
    int* cursor = rowptr + VP;                      // [VP]
    int2* pes   = (int2*)(cursor + VP);             // [E] {edge, src}
    int* part   = (int*)(pes + E_N);                // [128]
    int* pex    = part + 128;                       // [128]
    uint4* Bnp  = (uint4*)(pex + 128);              // [2560] packed nodeproj W
    uint4* Bw1b = Bnp + 2560;                       // [2][2048]
    uint4* Bw1a = Bw1b + 2 * 2048;                  // [2][512]
    uint4* Bw2  = Bw1a + 2 * 512;                   // [2][2048]
    uchar* U    = (uchar*)(Bw2 + 2 * 2048);         // [E][128] fp8 e4m3, perm order, permuted bytes
    float* out = (float*)d_out;

    const int NB = (V_N + 1023) / 1024;  // 98

    // --- weight pre-pack (frag-layout bf16) ---
    k_pack<<<10, 256, 0, stream>>>(npw, Bnp, 2560, 138);
    for (int l = 0; l < 2; ++l) {
        const float* W1b = w1 + (size_t)l * 144 * 128;
        const float* W1a = W1b + 128 * 128;
        k_pack<<<8, 256, 0, stream>>>(W1b, Bw1b + l * 2048, 2048, 128);
        k_pack<<<2, 256, 0, stream>>>(W1a, Bw1a + l * 512, 512, 16);
        k_pack<<<8, 256, 0, stream>>>(w2 + (size_t)l * 128 * 128, Bw2 + l * 2048, 2048, 128);
    }

    hipMemsetAsync(cnt, 0, VP * sizeof(int), stream);
    k_count<<<(E_N + 255) / 256, 256, 0, stream>>>(edst, cnt);
    k_scan1<<<NB, 256, 0, stream>>>(cnt, rowptr, part);
    k_scan2<<<1, 128, 0, stream>>>(part, pex, NB);
    k_scan3<<<(V_N + 255) / 256, 256, 0, stream>>>(rowptr, pex, cursor);
    k_scatter<<<(E_N + 255) / 256, 256, 0, stream>>>(esrc, edst, cursor, pes);
    k_nodeproj<<<NTILES, 256, 0, stream>>>(Z, meta, Bnp, npb, hb);

    for (int l = 0; l < 2; ++l) {
        k_gemm1<<<NTILES, 256, 0, stream>>>(hb, Bw1b + l * 2048, b1 + l * 128, tb);
        k_edge_mlp<<<E_N / 64, 256, 0, stream>>>(ea, pes, Bw1a + l * 512, U);
        k_edge_agg2<<<V_N / 4, 256, 0, stream>>>(tb, U, pes, rowptr, S);
        k_node_update<<<NTILES, 256, 0, stream>>>(S, hb, cnt, Bw2 + l * 2048,
                                                  b2 + l * 128, lng + l * 128, lnb + l * 128);
    }
    k_final<<<NVEH, 128, 0, stream>>>(hb, cur, veh, pw1, pb1, pw2, pb2, rog, rob, out);
}

// Round 12
// 543.213 us; speedup vs baseline: 1.4128x; 1.1189x over previous
//
#include <hip/hip_runtime.h>
#include <hip/hip_bf16.h>

#define V_N 100000
#define VP  100096          // padded to multiple of 64
#define E_N 800000
#define NVEH 16
#define LN_EPS 1e-5f
#define NTILES (VP / 64)    // 1564

typedef unsigned int uint;
typedef unsigned short ushort;
typedef unsigned char uchar;
typedef __attribute__((ext_vector_type(8))) short bf8_t;   // 8 bf16 in 4 VGPRs
typedef __attribute__((ext_vector_type(4))) float f4_t;

__device__ __forceinline__ float bf2f(ushort u) {
    union { uint i; float f; } c; c.i = ((uint)u) << 16; return c.f;
}
__device__ __forceinline__ ushort f2bf(float f) {
    union { float f; uint i; } c; c.f = f; uint x = c.i;
    return (ushort)((x + 0x7FFFu + ((x >> 16) & 1u)) >> 16);   // RNE
}
__device__ __forceinline__ uint pk2(float a, float b) {
    return (uint)f2bf(a) | ((uint)f2bf(b) << 16);
}

// ---------------- generic weight pre-pack: W[krows][128] f32 -> frag bf16 uint4 ----------------
__global__ __launch_bounds__(256) void k_pack(const float* __restrict__ W, uint4* __restrict__ dst,
                                              int nslots, int krows) {
    int slot = blockIdx.x * 256 + threadIdx.x;
    if (slot >= nslots) return;
    int ks = slot >> 9;
    int ct = (slot >> 6) & 7;
    int l  = slot & 63;
    int k0 = ks * 32 + ((l >> 4) << 3);
    int col = (ct << 4) + (l & 15);
    ushort u[8];
#pragma unroll
    for (int e = 0; e < 8; ++e) {
        int k = k0 + e;
        u[e] = (k < krows) ? f2bf(W[(size_t)k * 128 + col]) : (ushort)0;
    }
    uint4 p;
    p.x = (uint)u[0] | ((uint)u[1] << 16);
    p.y = (uint)u[2] | ((uint)u[3] << 16);
    p.z = (uint)u[4] | ((uint)u[5] << 16);
    p.w = (uint)u[6] | ((uint)u[7] << 16);
    dst[slot] = p;
}

// ---------------- in-degree count ----------------
__global__ __launch_bounds__(256) void k_count(const int* __restrict__ dst, int* __restrict__ cnt) {
    int i = blockIdx.x * blockDim.x + threadIdx.x;
    if (i < E_N) atomicAdd(&cnt[dst[i]], 1);
}

// ---------------- 3-kernel exclusive scan (1024 elems/block) ----------------
__global__ __launch_bounds__(256) void k_scan1(const int* __restrict__ cnt, int* __restrict__ rowptr,
                                               int* __restrict__ part) {
    __shared__ int sh[256];
    const int tid = threadIdx.x;
    const int base = blockIdx.x * 1024 + tid * 4;
    int v0 = (base + 0 < V_N) ? cnt[base + 0] : 0;
    int v1 = (base + 1 < V_N) ? cnt[base + 1] : 0;
    int v2 = (base + 2 < V_N) ? cnt[base + 2] : 0;
    int v3 = (base + 3 < V_N) ? cnt[base + 3] : 0;
    int s = v0 + v1 + v2 + v3;
    sh[tid] = s; __syncthreads();
    for (int off = 1; off < 256; off <<= 1) {
        int t = (tid >= off) ? sh[tid - off] : 0;
        __syncthreads();
        sh[tid] += t;
        __syncthreads();
    }
    int excl = sh[tid] - s;
    if (tid == 255) part[blockIdx.x] = sh[255];
    int run = excl;
    if (base + 0 < V_N) rowptr[base + 0] = run; run += v0;
    if (base + 1 < V_N) rowptr[base + 1] = run; run += v1;
    if (base + 2 < V_N) rowptr[base + 2] = run; run += v2;
    if (base + 3 < V_N) rowptr[base + 3] = run;
}

__global__ __launch_bounds__(128) void k_scan2(const int* __restrict__ part, int* __restrict__ pex, int nb) {
    __shared__ int sh[128];
    const int tid = threadIdx.x;
    int v = (tid < nb) ? part[tid] : 0;
    sh[tid] = v; __syncthreads();
    for (int off = 1; off < 128; off <<= 1) {
        int t = (tid >= off) ? sh[tid - off] : 0;
        __syncthreads();
        sh[tid] += t;
        __syncthreads();
    }
    if (tid < nb) pex[tid] = sh[tid] - v;
}

__global__ __launch_bounds__(256) void k_scan3(int* __restrict__ rowptr, const int* __restrict__ pex,
                                               int* __restrict__ cursor) {
    int i = blockIdx.x * 256 + threadIdx.x;
    if (i < V_N) {
        int rp = rowptr[i] + pex[i >> 10];
        rowptr[i] = rp;
        cursor[i] = rp;
    }
    if (i == 0) rowptr[V_N] = E_N;
}

__global__ __launch_bounds__(256) void k_scatter(const int* __restrict__ src, const int* __restrict__ dst,
                                                 int* __restrict__ cursor, int2* __restrict__ pes) {
    int e = blockIdx.x * 256 + threadIdx.x;
    if (e < E_N) {
        int d = dst[e];
        int p = atomicAdd(&cursor[d], 1);
        pes[p] = make_int2(e, src[e]);
    }
}

// ---------------- node projection: hb = bf16(concat(Z, meta, 0pad) @ Wp + bp) via MFMA ----------------
__global__ __launch_bounds__(256) void k_nodeproj(const float* __restrict__ Z, const float* __restrict__ meta,
                                                  const uint4* __restrict__ Bpk, const float* __restrict__ b,
                                                  ushort* __restrict__ hb) {
    __shared__ uint4 Bs4[2560];   // 5 ks x 8 ct x 64 lanes, 40 KB
    const int tid = threadIdx.x;
    for (int slot = tid; slot < 2560; slot += 256) Bs4[slot] = Bpk[slot];
    __syncthreads();
    const int lane = tid & 63, wid = tid >> 6;
    const int l15 = lane & 15, l4 = lane >> 4;
    float bcol[8];
#pragma unroll
    for (int ct = 0; ct < 8; ++ct) bcol[ct] = b[ct * 16 + l15];
    const int tile = blockIdx.x;
    int rowA = tile * 64 + wid * 16 + l15;
    int rowAc = rowA < V_N ? rowA : V_N - 1;      // clamp: avoid OOB input reads
    const float* zp = Z + (size_t)rowAc * 128;
    union { uint4 u; bf8_t b; } afr[5];
#pragma unroll
    for (int ks = 0; ks < 4; ++ks) {
        int k0 = ks * 32 + l4 * 8;
        float4 f0 = *(const float4*)(zp + k0);
        float4 f1 = *(const float4*)(zp + k0 + 4);
        afr[ks].u.x = pk2(f0.x, f0.y);
        afr[ks].u.y = pk2(f0.z, f0.w);
        afr[ks].u.z = pk2(f1.x, f1.y);
        afr[ks].u.w = pk2(f1.z, f1.w);
    }
    {
        const float* mp = meta + (size_t)rowAc * 10;
        int f0 = l4 * 8;
        ushort u[8];
#pragma unroll
        for (int e = 0; e < 8; ++e) {
            int f = f0 + e;
            u[e] = (f < 10) ? f2bf(mp[f]) : (ushort)0;
        }
        afr[4].u.x = (uint)u[0] | ((uint)u[1] << 16);
        afr[4].u.y = (uint)u[2] | ((uint)u[3] << 16);
        afr[4].u.z = (uint)u[4] | ((uint)u[5] << 16);
        afr[4].u.w = (uint)u[6] | ((uint)u[7] << 16);
    }
    f4_t acc[8];
#pragma unroll
    for (int ct = 0; ct < 8; ++ct) acc[ct] = (f4_t){bcol[ct], bcol[ct], bcol[ct], bcol[ct]};
#pragma unroll
    for (int ks = 0; ks < 5; ++ks) {
#pragma unroll
        for (int ct = 0; ct < 8; ++ct) {
            union { uint4 u; bf8_t b; } cb; cb.u = Bs4[(ks * 8 + ct) * 64 + lane];
            acc[ct] = __builtin_amdgcn_mfma_f32_16x16x32_bf16(afr[ks].b, cb.b, acc[ct], 0, 0, 0);
        }
    }
    const int rowC0 = tile * 64 + wid * 16 + l4 * 4;
#pragma unroll
    for (int ct = 0; ct < 8; ++ct) {
        int col = ct * 16 + l15;
#pragma unroll
        for (int r = 0; r < 4; ++r) {
            int row = rowC0 + r;
            if (row < V_N) hb[(size_t)row * 128 + col] = f2bf(acc[ct][r]);
        }
    }
}

// ---------------- GEMM1: tb = bf16(hb @ W1b + b1), MFMA; tb stored in PERMUTED order ----------------
// position sigma(col) = (col&15)*8 + (col>>4): lane's 8 cols (ct=0..7, fixed l15) are contiguous
__global__ __launch_bounds__(256) void k_gemm1(const ushort* __restrict__ hb, const uint4* __restrict__ Bpk,
                                               const float* __restrict__ b, ushort* __restrict__ tb) {
    __shared__ uint4 Bs4[2048];
    const int tid = threadIdx.x;
    for (int slot = tid; slot < 2048; slot += 256) Bs4[slot] = Bpk[slot];
    __syncthreads();
    const int lane = tid & 63, wid = tid >> 6;
    const int l15 = lane & 15, l4 = lane >> 4;
    float bcol[8];
#pragma unroll
    for (int ct = 0; ct < 8; ++ct) bcol[ct] = b[ct * 16 + l15];
    const int tile = blockIdx.x;
    const int rowA = tile * 64 + wid * 16 + l15;
    const uint4* ap = (const uint4*)(hb + (size_t)rowA * 128);
    f4_t acc[8];
#pragma unroll
    for (int ct = 0; ct < 8; ++ct) acc[ct] = (f4_t){bcol[ct], bcol[ct], bcol[ct], bcol[ct]};
#pragma unroll
    for (int ks = 0; ks < 4; ++ks) {
        union { uint4 u; bf8_t b; } ca; ca.u = ap[ks * 4 + l4];
#pragma unroll
        for (int ct = 0; ct < 8; ++ct) {
            union { uint4 u; bf8_t b; } cb; cb.u = Bs4[(ks * 8 + ct) * 64 + lane];
            acc[ct] = __builtin_amdgcn_mfma_f32_16x16x32_bf16(ca.b, cb.b, acc[ct], 0, 0, 0);
        }
    }
    const int rowC0 = tile * 64 + wid * 16 + l4 * 4;
#pragma unroll
    for (int r = 0; r < 4; ++r) {
        int row = rowC0 + r;
        if (row < V_N) {
            uint4 w;
            w.x = pk2(acc[0][r], acc[1][r]);
            w.y = pk2(acc[2][r], acc[3][r]);
            w.z = pk2(acc[4][r], acc[5][r]);
            w.w = pk2(acc[6][r], acc[7][r]);
            *(uint4*)(tb + (size_t)row * 128 + l15 * 8) = w;
        }
    }
}

// ---------------- edge MLP GEMM: U[i] = fp8(ea[pes[i].x] @ W1a), perm order, PERMUTED byte layout ----
// byte position sigma(col) = (col&15)*8 + (col>>4) -> each lane stores 8 contiguous bytes/row (uint2)
__global__ __launch_bounds__(256) void k_edge_mlp(const float* __restrict__ ea,
                                                  const int2* __restrict__ pes,
                                                  const uint4* __restrict__ Bpk,
                                                  uchar* __restrict__ U) {
    __shared__ uint4 Bs4[512];   // 8 ct x 64 lanes; K=32 (rows 0-15 real, 16-31 zero), 8 KB
    const int tid = threadIdx.x;
    for (int slot = tid; slot < 512; slot += 256) Bs4[slot] = Bpk[slot];
    __syncthreads();
    const int lane = tid & 63, wid = tid >> 6;
    const int l15 = lane & 15, l4 = lane >> 4;
    const long ebase = (long)blockIdx.x * 64 + wid * 16;   // 16 perm rows per wave
    union { uint4 u; bf8_t b; } afr;
    afr.u = make_uint4(0u, 0u, 0u, 0u);
    if (l4 < 2) {
        int eidx = pes[ebase + l15].x;
        const float* ep = ea + (size_t)eidx * 16 + l4 * 8;
        float4 f0 = *(const float4*)ep;
        float4 f1 = *(const float4*)(ep + 4);
        afr.u.x = pk2(f0.x, f0.y);
        afr.u.y = pk2(f0.z, f0.w);
        afr.u.z = pk2(f1.x, f1.y);
        afr.u.w = pk2(f1.z, f1.w);
    }
    f4_t acc[8];
#pragma unroll
    for (int ct = 0; ct < 8; ++ct) acc[ct] = (f4_t){0.f, 0.f, 0.f, 0.f};
#pragma unroll
    for (int ct = 0; ct < 8; ++ct) {
        union { uint4 u; bf8_t b; } cb; cb.u = Bs4[ct * 64 + lane];
        acc[ct] = __builtin_amdgcn_mfma_f32_16x16x32_bf16(afr.b, cb.b, acc[ct], 0, 0, 0);
    }
    const long rowC0 = ebase + l4 * 4;
#pragma unroll
    for (int r = 0; r < 4; ++r) {
        int p01 = __builtin_amdgcn_cvt_pk_fp8_f32(acc[0][r], acc[1][r], 0, false);
        int p23 = __builtin_amdgcn_cvt_pk_fp8_f32(acc[2][r], acc[3][r], 0, false);
        int p45 = __builtin_amdgcn_cvt_pk_fp8_f32(acc[4][r], acc[5][r], 0, false);
        int p67 = __builtin_amdgcn_cvt_pk_fp8_f32(acc[6][r], acc[7][r], 0, false);
        uint2 w;
        w.x = ((uint)p01 & 0xffffu) | ((uint)p23 << 16);
        w.y = ((uint)p45 & 0xffffu) | ((uint)p67 << 16);
        *(uint2*)(U + (size_t)(rowC0 + r) * 128 + l15 * 8) = w;
    }
}

// ---------------- edge aggregation: S[v] = bf16(mean_i relu(tb[src_i] + U[i])) ----------------
// lane owns PERMUTED positions (2*lane, 2*lane+1) = natural cols (c0, c0+16); tb & U both permuted
__global__ __launch_bounds__(256) void k_edge_agg2(const ushort* __restrict__ tb,
                                                   const uchar* __restrict__ U,
                                                   const int2* __restrict__ pes,
                                                   const int* __restrict__ rowptr,
                                                   ushort* __restrict__ S) {
    const int lane = threadIdx.x & 63;
    const int wid  = threadIdx.x >> 6;
    const int v = blockIdx.x * 4 + wid;
    if (v >= V_N) return;
    const int st = rowptr[v], en = rowptr[v + 1];
    const int p0 = 2 * lane;                               // permuted position
    const int c0 = ((p0 & 7) << 4) | (p0 >> 3);            // natural col of p0; p0+1 -> c0+16
    float a0 = 0.f, a1 = 0.f;
    for (int i0 = st; i0 < en; i0 += 8) {
        const int n = en - i0;
        int idx[8];
#pragma unroll
        for (int j = 0; j < 8; ++j) idx[j] = (j < n) ? (i0 + j) : i0;
        int s[8];
#pragma unroll
        for (int j = 0; j < 8; ++j) s[j] = pes[idx[j]].y;
        uint tv[8]; ushort uv[8];
#pragma unroll
        for (int j = 0; j < 8; ++j) {
            tv[j] = *(const uint*)(tb + (size_t)s[j] * 128 + p0);
            uv[j] = *(const ushort*)(U + (size_t)idx[j] * 128 + p0);
        }
#pragma unroll
        for (int j = 0; j < 8; ++j) {
            auto uf = __builtin_amdgcn_cvt_pk_f32_fp8((int)uv[j], false);
            float q0 = bf2f((ushort)(tv[j] & 0xffffu)) + uf[0];
            float q1 = bf2f((ushort)(tv[j] >> 16)) + uf[1];
            if (j < n) { a0 += fmaxf(q0, 0.f); a1 += fmaxf(q1, 0.f); }
        }
    }
    int dg = en - st;
    float inv = 1.f / (float)(dg > 1 ? dg : 1);
    S[(size_t)v * 128 + c0]      = f2bf(a0 * inv);
    S[(size_t)v * 128 + c0 + 16] = f2bf(a1 * inv);
}

// ---------------- node update: hb = bf16(LN(hb + S@W2 + b2*mask)), MFMA + fused LN ----------------
__global__ __launch_bounds__(256) void k_node_update(const ushort* __restrict__ S, ushort* __restrict__ hb,
                                                     const int* __restrict__ cnt,
                                                     const uint4* __restrict__ Bpk, const float* __restrict__ b2,
                                                     const float* __restrict__ g, const float* __restrict__ bt) {
    __shared__ uint4 Bs4[2048];
    const int tid = threadIdx.x;
    for (int slot = tid; slot < 2048; slot += 256) Bs4[slot] = Bpk[slot];
    __syncthreads();
    const int lane = tid & 63, wid = tid >> 6;
    const int l15 = lane & 15, l4 = lane >> 4;
    float b2c[8], gc[8], btc[8];
#pragma unroll
    for (int ct = 0; ct < 8; ++ct) {
        int col = ct * 16 + l15;
        b2c[ct] = b2[col]; gc[ct] = g[col]; btc[ct] = bt[col];
    }
    const int tile = blockIdx.x;
    const int rowA = tile * 64 + wid * 16 + l15;
    const uint4* ap = (const uint4*)(S + (size_t)rowA * 128);
    f4_t acc[8];
#pragma unroll
    for (int ct = 0; ct < 8; ++ct) acc[ct] = (f4_t){0.f, 0.f, 0.f, 0.f};
#pragma unroll
    for (int ks = 0; ks < 4; ++ks) {
        union { uint4 u; bf8_t b; } ca; ca.u = ap[ks * 4 + l4];
#pragma unroll
        for (int ct = 0; ct < 8; ++ct) {
            union { uint4 u; bf8_t b; } cb; cb.u = Bs4[(ks * 8 + ct) * 64 + lane];
            acc[ct] = __builtin_amdgcn_mfma_f32_16x16x32_bf16(ca.b, cb.b, acc[ct], 0, 0, 0);
        }
    }
    const int rowC0 = tile * 64 + wid * 16 + l4 * 4;
    float mask[4];
#pragma unroll
    for (int r = 0; r < 4; ++r) {
        int row = rowC0 + r;
        int dg = (row < V_N) ? cnt[row] : 0;
        mask[r] = (dg > 0) ? 1.f : 0.f;
    }
    float x[8][4];
#pragma unroll
    for (int ct = 0; ct < 8; ++ct) {
        int col = ct * 16 + l15;
#pragma unroll
        for (int r = 0; r < 4; ++r) {
            float hv = bf2f(hb[(size_t)(rowC0 + r) * 128 + col]);
            x[ct][r] = hv + acc[ct][r] + b2c[ct] * mask[r];
        }
    }
#pragma unroll
    for (int r = 0; r < 4; ++r) {
        float s = 0.f;
#pragma unroll
        for (int ct = 0; ct < 8; ++ct) s += x[ct][r];
        s += __shfl_xor(s, 1); s += __shfl_xor(s, 2);
        s += __shfl_xor(s, 4); s += __shfl_xor(s, 8);
        float mean = s * (1.f / 128.f);
        float vv = 0.f;
#pragma unroll
        for (int ct = 0; ct < 8; ++ct) { float d = x[ct][r] - mean; vv = fmaf(d, d, vv); }
        vv += __shfl_xor(vv, 1); vv += __shfl_xor(vv, 2);
        vv += __shfl_xor(vv, 4); vv += __shfl_xor(vv, 8);
        float rs = rsqrtf(vv * (1.f / 128.f) + LN_EPS);
        int row = rowC0 + r;
        bool ok = row < V_N;
#pragma unroll
        for (int ct = 0; ct < 8; ++ct) {
            int col = ct * 16 + l15;
            float y = (x[ct][r] - mean) * rs * gc[ct] + btc[ct];
            if (ok) hb[(size_t)row * 128 + col] = f2bf(y);
        }
    }
}

// ---------------- final: out = LN(hb[cur] + props MLP) ----------------
__global__ __launch_bounds__(128) void k_final(const ushort* __restrict__ hb, const int* __restrict__ cur,
                                               const float* __restrict__ veh,
                                               const float* __restrict__ pw1, const float* __restrict__ pb1,
                                               const float* __restrict__ pw2, const float* __restrict__ pb2,
                                               const float* __restrict__ g, const float* __restrict__ bt,
                                               float* __restrict__ out) {
    __shared__ float hid[128];
    __shared__ float red[2];
    const int i = blockIdx.x;
    const int j = threadIdx.x;
    float a = pb1[j];
#pragma unroll
    for (int f = 0; f < 8; ++f) a = fmaf(veh[i * 8 + f], pw1[f * 128 + j], a);
    hid[j] = fmaxf(a, 0.f);
    __syncthreads();
    float o = pb2[j] + bf2f(hb[(size_t)cur[i] * 128 + j]);
    for (int k = 0; k < 128; ++k) o = fmaf(hid[k], pw2[k * 128 + j], o);
    const int lane = j & 63, wid = j >> 6;
    float s = o;
#pragma unroll
    for (int off = 32; off > 0; off >>= 1) s += __shfl_xor(s, off);
    if (lane == 0) red[wid] = s;
    __syncthreads();
    float mean = (red[0] + red[1]) * (1.f / 128.f);
    __syncthreads();
    float d = o - mean;
    float vv = d * d;
#pragma unroll
    for (int off = 32; off > 0; off >>= 1) vv += __shfl_xor(vv, off);
    if (lane == 0) red[wid] = vv;
    __syncthreads();
    float var = (red[0] + red[1]) * (1.f / 128.f);
    float r = rsqrtf(var + LN_EPS);
    out[i * 128 + j] = d * r * g[j] + bt[j];
}

extern "C" void kernel_launch(void* const* d_in, const int* in_sizes, int n_in,
                              void* d_out, int out_size, void* d_ws, size_t ws_size,
                              hipStream_t stream) {
    const float* Z    = (const float*)d_in[0];
    const float* meta = (const float*)d_in[1];
    const float* veh  = (const float*)d_in[2];
    const float* ea   = (const float*)d_in[3];
    const int*   esrc = (const int*)d_in[4];
    const int*   edst = (const int*)d_in[5];
    const int*   cur  = (const int*)d_in[6];
    const float* npw  = (const float*)d_in[7];
    const float* npb  = (const float*)d_in[8];
    const float* w1   = (const float*)d_in[9];
    const float* b1   = (const float*)d_in[10];
    const float* w2   = (const float*)d_in[11];
    const float* b2   = (const float*)d_in[12];
    const float* lng  = (const float*)d_in[13];
    const float* lnb  = (const float*)d_in[14];
    const float* pw1  = (const float*)d_in[15];
    const float* pb1  = (const float*)d_in[16];
    const float* pw2  = (const float*)d_in[17];
    const float* pb2  = (const float*)d_in[18];
    const float* rog  = (const float*)d_in[19];
    const float* rob  = (const float*)d_in[20];

    ushort* hb = (ushort*)d_ws;                     // [VP][128] bf16 (natural)
    ushort* tb = hb + (size_t)VP * 128;             // [VP][128] bf16 (PERMUTED sigma order)
    ushort* S  = tb + (size_t)VP * 128;             // [VP][128] bf16 (natural)
    int* cnt    = (int*)(S + (size_t)VP * 128);     // [VP]
    int* rowptr = cnt + VP;                         // [V+1]
    int* cursor = rowptr + VP;                      // [VP]
    int2* pes   = (int2*)(cursor + VP);             // [E] {edge, src}
    int* part   = (int*)(pes + E_N);                // [128]
    int* pex    = part + 128;                       // [128]
    uint4* Bnp  = (uint4*)(pex + 128);              // [2560] packed nodeproj W
    uint4* Bw1b = Bnp + 2560;                       // [2][2048]
    uint4* Bw1a = Bw1b + 2 * 2048;                  // [2][512]
    uint4* Bw2  = Bw1a + 2 * 512;                   // [2][2048]
    uchar* U    = (uchar*)(Bw2 + 2 * 2048);         // [E][128] fp8 e4m3, perm order, permuted bytes
    float* out = (float*)d_out;

    const int NB = (V_N + 1023) / 1024;  // 98

    // --- weight pre-pack (frag-layout bf16) ---
    k_pack<<<10, 256, 0, stream>>>(npw, Bnp, 2560, 138);
    for (int l = 0; l < 2; ++l) {
        const float* W1b = w1 + (size_t)l * 144 * 128;
        const float* W1a = W1b + 128 * 128;
        k_pack<<<8, 256, 0, stream>>>(W1b, Bw1b + l * 2048, 2048, 128);
        k_pack<<<2, 256, 0, stream>>>(W1a, Bw1a + l * 512, 512, 16);
        k_pack<<<8, 256, 0, stream>>>(w2 + (size_t)l * 128 * 128, Bw2 + l * 2048, 2048, 128);
    }

    hipMemsetAsync(cnt, 0, VP * sizeof(int), stream);
    k_count<<<(E_N + 255) / 256, 256, 0, stream>>>(edst, cnt);
    k_scan1<<<NB, 256, 0, stream>>>(cnt, rowptr, part);
    k_scan2<<<1, 128, 0, stream>>>(part, pex, NB);
    k_scan3<<<(V_N + 255) / 256, 256, 0, stream>>>(rowptr, pex, cursor);
    k_scatter<<<(E_N + 255) / 256, 256, 0, stream>>>(esrc, edst, cursor, pes);
    k_nodeproj<<<NTILES, 256, 0, stream>>>(Z, meta, Bnp, npb, hb);

    for (int l = 0; l < 2; ++l) {
        k_gemm1<<<NTILES, 256, 0, stream>>>(hb, Bw1b + l * 2048, b1 + l * 128, tb);
        k_edge_mlp<<<E_N / 64, 256, 0, stream>>>(ea, pes, Bw1a + l * 512, U);
        k_edge_agg2<<<V_N / 4, 256, 0, stream>>>(tb, U, pes, rowptr, S);
        k_node_update<<<NTILES, 256, 0, stream>>>(S, hb, cnt, Bw2 + l * 2048,
                                                  b2 + l * 128, lng + l * 128, lnb + l * 128);
    }
    k_final<<<NVEH, 128, 0, stream>>>(hb, cur, veh, pw1, pb1, pw2, pb2, rog, rob, out);
}